// Round 13
// baseline (209.833 us; speedup 1.0000x reference)
//
#include <hip/hip_runtime.h>
#include <hip/hip_fp16.h>
#include <math.h>

typedef _Float16 f16x8 __attribute__((ext_vector_type(8)));
typedef _Float16 f16x4 __attribute__((ext_vector_type(4)));
typedef float f32x4 __attribute__((ext_vector_type(4)));

__device__ __forceinline__ int f2oi(float f) {
    int i = __float_as_int(f);
    return i >= 0 ? i : (i ^ 0x7FFFFFFF);
}
__device__ __forceinline__ float oi2f(int i) {
    return __int_as_float(i >= 0 ? i : (i ^ 0x7FFFFFFF));
}

// ---------- MFMA GEMM + fused logits + fused global-max ----------
template<int MT, int H, bool XF16>
__global__ __launch_bounds__(256) void gemm_mfma(const void* __restrict__ Xv,
                                                 const float* __restrict__ W,
                                                 const float* __restrict__ a_src,
                                                 const float* __restrict__ a_dst,
                                                 __half* __restrict__ Hout, int Mout,
                                                 float* __restrict__ als,
                                                 float* __restrict__ ald,
                                                 int* __restrict__ mint, int N) {
    constexpr int LDSB = (MT * 4096 > 16384) ? MT * 4096 : 16384;
    constexpr int HST = (MT == 8) ? 256 : 128;
    __shared__ char ldsb[LDSB];
    __shared__ int lmax[8];

    int tid = threadIdx.x;
    if (tid < 8) lmax[tid] = (int)0x80000000;

    const int nf4 = 16 * MT * 32;
    for (int idx = tid; idx < nf4; idx += 256) {
        int r = idx >> 5, c = idx & 31;
        float4 w = (r < Mout) ? reinterpret_cast<const float4*>(W)[(size_t)r * 32 + c]
                              : make_float4(0.f, 0.f, 0.f, 0.f);
        f16x4 hv;
        hv[0] = (_Float16)w.x; hv[1] = (_Float16)w.y;
        hv[2] = (_Float16)w.z; hv[3] = (_Float16)w.w;
        int byte = r * 256 + ((c * 8) ^ ((r & 7) << 4));
        *reinterpret_cast<f16x4*>(&ldsb[byte]) = hv;
    }
    __syncthreads();

    int l = tid & 63, wv = tid >> 6;
    int lr = l & 15, lk = l >> 4;
    f32x4 acc[2][MT];
#pragma unroll
    for (int rt = 0; rt < 2; rt++)
#pragma unroll
        for (int c = 0; c < MT; c++) acc[rt][c] = (f32x4){0.f, 0.f, 0.f, 0.f};

    const float* xpf[2];
    const __half* xph[2];
#pragma unroll
    for (int rt = 0; rt < 2; rt++) {
        int rg = blockIdx.x * 128 + rt * 64 + wv * 16 + lr;
        if (rg >= N) rg = N - 1;
        if (XF16) xph[rt] = (const __half*)Xv + (size_t)rg * 128 + lk * 8;
        else      xpf[rt] = (const float*)Xv + (size_t)rg * 128 + lk * 8;
    }

#pragma unroll
    for (int k0 = 0; k0 < 128; k0 += 32) {
        f16x8 a[2];
#pragma unroll
        for (int rt = 0; rt < 2; rt++) {
            if (XF16) {
                a[rt] = *reinterpret_cast<const f16x8*>(xph[rt] + k0);
            } else {
                float4 x0 = *reinterpret_cast<const float4*>(xpf[rt] + k0);
                float4 x1 = *reinterpret_cast<const float4*>(xpf[rt] + k0 + 4);
                a[rt][0] = (_Float16)x0.x; a[rt][1] = (_Float16)x0.y;
                a[rt][2] = (_Float16)x0.z; a[rt][3] = (_Float16)x0.w;
                a[rt][4] = (_Float16)x1.x; a[rt][5] = (_Float16)x1.y;
                a[rt][6] = (_Float16)x1.z; a[rt][7] = (_Float16)x1.w;
            }
        }
#pragma unroll
        for (int c = 0; c < MT; c++) {
            int n = 16 * c + lr;
            int byte = n * 256 + (((k0 + lk * 8) * 2) ^ ((n & 7) << 4));
            f16x8 b = *reinterpret_cast<const f16x8*>(&ldsb[byte]);
            acc[0][c] = __builtin_amdgcn_mfma_f32_16x16x32_f16(a[0], b, acc[0][c], 0, 0, 0);
            acc[1][c] = __builtin_amdgcn_mfma_f32_16x16x32_f16(a[1], b, acc[1][c], 0, 0, 0);
        }
    }
    __syncthreads();

#pragma unroll
    for (int rt = 0; rt < 2; rt++)
#pragma unroll
        for (int c = 0; c < MT; c++)
#pragma unroll
            for (int r = 0; r < 4; r++) {
                int rowl = rt * 64 + wv * 16 + lk * 4 + r;
                int col = 16 * c + lr;
                int byte = rowl * HST + ((col * 2) ^ ((rowl & 7) << 4));
                *reinterpret_cast<__half*>(&ldsb[byte]) = __float2half(acc[rt][c][r]);
            }
    __syncthreads();

    int row = tid >> 1, seg = tid & 1;
    int rowg = blockIdx.x * 128 + row;
    if (rowg < N) {
        const int rowB = Mout * 2;
        int segstart = (MT == 8) ? seg * 128 : seg * 48;
        int nch = (MT == 8) ? 8 : (seg ? 2 : 3);
        float hs[H], hd[H];
#pragma unroll
        for (int h = 0; h < H; h++) { hs[h] = 0.f; hd[h] = 0.f; }
        for (int i = 0; i < nch; i++) {
            int cb = segstart + i * 16;
            f16x8 v = *reinterpret_cast<const f16x8*>(
                &ldsb[row * HST + (cb ^ ((row & 7) << 4))]);
            *reinterpret_cast<f16x8*>((char*)Hout + (size_t)rowg * rowB + cb) = v;
            int hh = (H == 1) ? 0 : (cb >> 6);
            int colb = cb >> 1;
            float ps = 0.f, pd = 0.f;
#pragma unroll
            for (int j = 0; j < 8; j++) {
                float f = (float)v[j];
                ps = fmaf(f, a_src[colb + j], ps);
                pd = fmaf(f, a_dst[colb + j], pd);
            }
            hs[hh] += ps; hd[hh] += pd;
        }
        if (H == 4) {
#pragma unroll
            for (int t = 0; t < 2; t++) {
                int hh = 2 * seg + t;
                als[rowg * 4 + hh] = hs[hh];
                ald[rowg * 4 + hh] = hd[hh];
                atomicMax(&lmax[hh], f2oi(hs[hh]));
                atomicMax(&lmax[4 + hh], f2oi(hd[hh]));
            }
        } else {
            float s = hs[0] + __shfl_xor(hs[0], 1, 64);
            float d = hd[0] + __shfl_xor(hd[0], 1, 64);
            if (seg == 0) {
                als[rowg] = s; ald[rowg] = d;
                atomicMax(&lmax[0], f2oi(s));
                atomicMax(&lmax[4], f2oi(d));
            }
        }
    }
    __syncthreads();
    if (tid < H) atomicMax(&mint[tid], lmax[tid]);
    if (tid >= 8 && tid < 8 + H) atomicMax(&mint[4 + tid - 8], lmax[4 + tid - 8]);
}

// ---------- atomic-free CSR build (packed src<<16|dst pairs; N < 65536) ----------
__global__ __launch_bounds__(256) void p1_hist(const int* __restrict__ src,
                                               const int* __restrict__ dst,
                                               int E_real, int E_tot, int NB, int NBLK,
                                               int EPB, int* __restrict__ cntmat,
                                               int* __restrict__ mint) {
    if (blockIdx.x == 0 && threadIdx.x < 24) mint[threadIdx.x] = (int)0x80000000;
    __shared__ int hist[1024];
    for (int i = threadIdx.x; i < NB; i += 256) hist[i] = 0;
    __syncthreads();
    int e0 = blockIdx.x * EPB;
    int e1 = min(e0 + EPB, E_tot);
    for (int e = e0 + threadIdx.x; e < e1; e += 256) {
        int d = (e < E_real) ? dst[e] : e - E_real;
        atomicAdd(&hist[d >> 6], 1);
    }
    __syncthreads();
    for (int b = threadIdx.x; b < NB; b += 256)
        cntmat[b * NBLK + blockIdx.x] = hist[b];
}

// parallel Hillis-Steele scan of each bucket's 208 block-counts
__global__ __launch_bounds__(256) void p_scancols(int* __restrict__ cntmat,
                                                  int* __restrict__ colTot, int NBLK) {
    __shared__ int sh[256];
    int b = blockIdx.x;
    int t = threadIdx.x;
    int v = (t < NBLK) ? cntmat[b * NBLK + t] : 0;
    sh[t] = v;
    __syncthreads();
    for (int off = 1; off < 256; off <<= 1) {
        int u = (t >= off) ? sh[t - off] : 0;
        __syncthreads();
        sh[t] += u;
        __syncthreads();
    }
    if (t < NBLK) cntmat[b * NBLK + t] = sh[t] - v;   // exclusive
    if (t == 255) colTot[b] = sh[255];
}

__global__ __launch_bounds__(256) void p_scancoarse(const int* __restrict__ colTot,
                                                    int* __restrict__ coarseOff,
                                                    int* __restrict__ offsets,
                                                    int NB, int N, int E_tot) {
    __shared__ int sh[256];
    int t = threadIdx.x, base = t * 4;
    int v0 = 0, v1 = 0, v2 = 0, v3 = 0;
    if (base + 0 < NB) v0 = colTot[base + 0];
    if (base + 1 < NB) v1 = colTot[base + 1];
    if (base + 2 < NB) v2 = colTot[base + 2];
    if (base + 3 < NB) v3 = colTot[base + 3];
    int s = v0 + v1 + v2 + v3;
    sh[t] = s;
    __syncthreads();
    for (int off = 1; off < 256; off <<= 1) {
        int u = (t >= off) ? sh[t - off] : 0;
        __syncthreads();
        sh[t] += u;
        __syncthreads();
    }
    int run = sh[t] - s;
    if (base + 0 < NB) { coarseOff[base + 0] = run; run += v0; }
    if (base + 1 < NB) { coarseOff[base + 1] = run; run += v1; }
    if (base + 2 < NB) { coarseOff[base + 2] = run; run += v2; }
    if (base + 3 < NB) { coarseOff[base + 3] = run; }
    if (t == 255) { coarseOff[NB] = sh[255]; offsets[N] = E_tot; }
}

__global__ __launch_bounds__(256) void p2_scatter(const int* __restrict__ src,
                                                  const int* __restrict__ dst,
                                                  int E_real, int E_tot, int NB, int NBLK,
                                                  int EPB, const int* __restrict__ cntmat,
                                                  const int* __restrict__ coarseOff,
                                                  int* __restrict__ pairs) {
    __shared__ int cur[1024];
    for (int b = threadIdx.x; b < NB; b += 256)
        cur[b] = coarseOff[b] + cntmat[b * NBLK + blockIdx.x];
    __syncthreads();
    int e0 = blockIdx.x * EPB;
    int e1 = min(e0 + EPB, E_tot);
    for (int e = e0 + threadIdx.x; e < e1; e += 256) {
        int s, d;
        if (e < E_real) { s = src[e]; d = dst[e]; } else { s = d = e - E_real; }
        int pos = atomicAdd(&cur[d >> 6], 1);
        pairs[pos] = (s << 16) | d;
    }
}

__global__ __launch_bounds__(256) void p3_bucket(const int* __restrict__ pairs,
                                                 const int* __restrict__ coarseOff,
                                                 int NB, int N, int* __restrict__ offsets,
                                                 int* __restrict__ csr_src) {
    __shared__ int lh[64], lc[64];
    int b = blockIdx.x;
    int beg = coarseOff[b], end = coarseOff[b + 1];
    int t = threadIdx.x;
    if (t < 64) lh[t] = 0;
    __syncthreads();
    for (int i = beg + t; i < end; i += 256)
        atomicAdd(&lh[pairs[i] & 63], 1);
    __syncthreads();
    if (t < 64) {
        int v = lh[t];
        int run = v;
#pragma unroll
        for (int off = 1; off < 64; off <<= 1) {
            int o = __shfl_up(run, off, 64);
            if (t >= off) run += o;
        }
        int ex = run - v;
        lc[t] = ex;
        int node = b * 64 + t;
        if (node < N) offsets[node] = beg + ex;
    }
    __syncthreads();
    for (int i = beg + t; i < end; i += 256) {
        int pk = pairs[i];
        int pos = atomicAdd(&lc[pk & 63], 1);
        csr_src[beg + pos] = ((unsigned)pk) >> 16;
    }
}

// ---------- GAT aggregate, layers 0/1 (H=4,C=32): 8 edges in flight, fp16 out ----------
__global__ __launch_bounds__(256) void gat_agg128(const int* __restrict__ offsets,
                                                  const int* __restrict__ csr_src,
                                                  const __half* __restrict__ h,
                                                  const float* __restrict__ als,
                                                  const float* __restrict__ ald,
                                                  const int* __restrict__ mint,
                                                  const float* __restrict__ bias,
                                                  __half* __restrict__ out, int N) {
    __shared__ float wlds[4][64][4];
    __shared__ int   slds[4][64];
    int wid = threadIdx.x >> 6;
    int lane = threadIdx.x & 63;
    int g = lane >> 4, j = lane & 15, hd = j >> 2;
    int gwid = (blockIdx.x * 256 + threadIdx.x) >> 6;
    int nWaves = (gridDim.x * 256) >> 6;
    const char* hb = (const char*)h;
    const float4* als4 = (const float4*)als;
    const float4* ald4 = (const float4*)ald;

    float4 shiftv;
    {
        float v;
        v = oi2f(mint[0]) + oi2f(mint[4]); shiftv.x = v > 0.f ? v : 0.2f * v;
        v = oi2f(mint[1]) + oi2f(mint[5]); shiftv.y = v > 0.f ? v : 0.2f * v;
        v = oi2f(mint[2]) + oi2f(mint[6]); shiftv.z = v > 0.f ? v : 0.2f * v;
        v = oi2f(mint[3]) + oi2f(mint[7]); shiftv.w = v > 0.f ? v : 0.2f * v;
    }
    float4 bv0 = ((const float4*)bias)[j * 2];
    float4 bv1 = ((const float4*)bias)[j * 2 + 1];

    for (int n = gwid; n < N; n += nWaves) {
        int beg = offsets[n], end = offsets[n + 1];
        float4 adn = ald4[n];
        float acc[8];
#pragma unroll
        for (int k = 0; k < 8; k++) acc[k] = 0.f;
        float den = 0.f;

        for (int c0 = beg; c0 < end; c0 += 64) {
            int e = c0 + lane;
            int s = 0;
            float4 w = make_float4(0.f, 0.f, 0.f, 0.f);
            if (e < end) {
                s = csr_src[e];
                float4 a4 = als4[s];
                float v;
                v = a4.x + adn.x; v = v > 0.f ? v : 0.2f * v; w.x = __expf(v - shiftv.x);
                v = a4.y + adn.y; v = v > 0.f ? v : 0.2f * v; w.y = __expf(v - shiftv.y);
                v = a4.z + adn.z; v = v > 0.f ? v : 0.2f * v; w.z = __expf(v - shiftv.z);
                v = a4.w + adn.w; v = v > 0.f ? v : 0.2f * v; w.w = __expf(v - shiftv.w);
            }
            *reinterpret_cast<float4*>(&wlds[wid][lane][0]) = w;
            slds[wid][lane] = s;
            int cnt = end - c0; if (cnt > 64) cnt = 64;
            int quads = (cnt + 3) >> 2;
            int q = 0;
            for (; q + 2 <= quads; q += 2) {
                int ec0 = q * 4 + g, ec1 = ec0 + 4;
                int s0 = slds[wid][ec0], s1 = slds[wid][ec1];
                float w0 = wlds[wid][ec0][hd], w1 = wlds[wid][ec1][hd];
                f16x8 hv0 = *reinterpret_cast<const f16x8*>(
                    hb + (unsigned)(s0 * 256 + j * 16));
                f16x8 hv1 = *reinterpret_cast<const f16x8*>(
                    hb + (unsigned)(s1 * 256 + j * 16));
                den += w0 + w1;
#pragma unroll
                for (int k = 0; k < 8; k++)
                    acc[k] = fmaf((float)hv0[k], w0, fmaf((float)hv1[k], w1, acc[k]));
            }
            if (q < quads) {
                int ec = q * 4 + g;
                int s0 = slds[wid][ec];
                float w0 = wlds[wid][ec][hd];
                f16x8 hv = *reinterpret_cast<const f16x8*>(
                    hb + (unsigned)(s0 * 256 + j * 16));
                den += w0;
#pragma unroll
                for (int k = 0; k < 8; k++)
                    acc[k] = fmaf((float)hv[k], w0, acc[k]);
            }
        }
#pragma unroll
        for (int off = 16; off <= 32; off <<= 1) {
            den += __shfl_xor(den, off, 64);
#pragma unroll
            for (int k = 0; k < 8; k++) acc[k] += __shfl_xor(acc[k], off, 64);
        }
        if (g == 0) {
            float inv = 1.f / den;
            f16x8 ov;
            float bvv[8] = {bv0.x, bv0.y, bv0.z, bv0.w, bv1.x, bv1.y, bv1.z, bv1.w};
#pragma unroll
            for (int k = 0; k < 8; k++) {
                float r = acc[k] * inv + bvv[k];
                r = r > 0.f ? r : __expf(r) - 1.f;
                ov[k] = (_Float16)r;
            }
            *reinterpret_cast<f16x8*>((char*)out + (size_t)n * 256 + j * 16) = ov;
        }
    }
}

// ---------- GAT aggregate + log_softmax, layer 2 (H=1,C=40) ----------
__global__ __launch_bounds__(256) void gat_agg40_lsm(const int* __restrict__ offsets,
                                                     const int* __restrict__ csr_src,
                                                     const __half* __restrict__ h,
                                                     const float* __restrict__ als,
                                                     const float* __restrict__ ald,
                                                     const int* __restrict__ mint,
                                                     const float* __restrict__ b2,
                                                     float* __restrict__ out, int N) {
    __shared__ float wlds[4][64];
    __shared__ int   slds[4][64];
    int wid = threadIdx.x >> 6;
    int lane = threadIdx.x & 63;
    int g = lane >> 4, j = lane & 15;
    int gwid = (blockIdx.x * 256 + threadIdx.x) >> 6;
    int nWaves = (gridDim.x * 256) >> 6;
    const char* hb = (const char*)h;

    float shift;
    {
        float v = oi2f(mint[0]) + oi2f(mint[4]);
        shift = v > 0.f ? v : 0.2f * v;
    }
    float4 bv = (j < 10) ? ((const float4*)b2)[j] : make_float4(0.f, 0.f, 0.f, 0.f);

    for (int n = gwid; n < N; n += nWaves) {
        int beg = offsets[n], end = offsets[n + 1];
        float adn = ald[n];
        float acc[4];
#pragma unroll
        for (int k = 0; k < 4; k++) acc[k] = 0.f;
        float den = 0.f;

        for (int c0 = beg; c0 < end; c0 += 64) {
            int e = c0 + lane;
            int s = 0;
            float wv = 0.f;
            if (e < end) {
                s = csr_src[e];
                float v = als[s] + adn; v = v > 0.f ? v : 0.2f * v;
                wv = __expf(v - shift);
            }
            wlds[wid][lane] = wv;
            slds[wid][lane] = s;
            int cnt = end - c0; if (cnt > 64) cnt = 64;
            int quads = (cnt + 3) >> 2;
            int q = 0;
            for (; q + 2 <= quads; q += 2) {
                int ec0 = q * 4 + g, ec1 = ec0 + 4;
                int s0 = slds[wid][ec0], s1 = slds[wid][ec1];
                float w0 = wlds[wid][ec0], w1 = wlds[wid][ec1];
                den += w0 + w1;
                if (j < 10) {
                    f16x4 hv0 = *reinterpret_cast<const f16x4*>(
                        hb + (unsigned)(s0 * 80 + j * 8));
                    f16x4 hv1 = *reinterpret_cast<const f16x4*>(
                        hb + (unsigned)(s1 * 80 + j * 8));
#pragma unroll
                    for (int k = 0; k < 4; k++)
                        acc[k] = fmaf((float)hv0[k], w0, fmaf((float)hv1[k], w1, acc[k]));
                }
            }
            if (q < quads) {
                int ec = q * 4 + g;
                int s0 = slds[wid][ec];
                float w0 = wlds[wid][ec];
                den += w0;
                if (j < 10) {
                    f16x4 hv = *reinterpret_cast<const f16x4*>(
                        hb + (unsigned)(s0 * 80 + j * 8));
#pragma unroll
                    for (int k = 0; k < 4; k++)
                        acc[k] = fmaf((float)hv[k], w0, acc[k]);
                }
            }
        }
#pragma unroll
        for (int off = 16; off <= 32; off <<= 1) {
            den += __shfl_xor(den, off, 64);
#pragma unroll
            for (int k = 0; k < 4; k++) acc[k] += __shfl_xor(acc[k], off, 64);
        }
        float inv = 1.f / den;
        float val[4];
        float m = -INFINITY;
#pragma unroll
        for (int k = 0; k < 4; k++) {
            val[k] = (j < 10) ? acc[k] * inv + ((const float*)&bv)[k] : -INFINITY;
            m = fmaxf(m, val[k]);
        }
#pragma unroll
        for (int off = 8; off >= 1; off >>= 1) m = fmaxf(m, __shfl_xor(m, off, 64));
        float pe = 0.f;
#pragma unroll
        for (int k = 0; k < 4; k++)
            if (j < 10) pe += __expf(val[k] - m);
#pragma unroll
        for (int off = 8; off >= 1; off >>= 1) pe += __shfl_xor(pe, off, 64);
        if (g == 0 && j < 10) {
            float lsum = __logf(pe);
            float4 o;
            o.x = val[0] - m - lsum;
            o.y = val[1] - m - lsum;
            o.z = val[2] - m - lsum;
            o.w = val[3] - m - lsum;
            ((float4*)(out + (size_t)n * 40))[j] = o;
        }
    }
}

extern "C" void kernel_launch(void* const* d_in, const int* in_sizes, int n_in,
                              void* d_out, int out_size, void* d_ws, size_t ws_size,
                              hipStream_t stream) {
    const float* x      = (const float*)d_in[0];
    const int*   ei     = (const int*)d_in[1];
    const float* W0     = (const float*)d_in[2];
    const float* a_src0 = (const float*)d_in[3];
    const float* a_dst0 = (const float*)d_in[4];
    const float* b0     = (const float*)d_in[5];
    const float* W1     = (const float*)d_in[6];
    const float* a_src1 = (const float*)d_in[7];
    const float* a_dst1 = (const float*)d_in[8];
    const float* b1     = (const float*)d_in[9];
    const float* W2     = (const float*)d_in[10];
    const float* a_src2 = (const float*)d_in[11];
    const float* a_dst2 = (const float*)d_in[12];
    const float* b2     = (const float*)d_in[13];

    const int N = in_sizes[0] / 128;          // 50000  (< 65536, required for packing)
    const int E_real = in_sizes[1] / 2;       // 800000
    const int E_tot = E_real + N;
    const int* src = ei;
    const int* dst = ei + E_real;

    const int EPB  = 4096;
    const int NBLK = (E_tot + EPB - 1) / EPB; // 208
    const int NB   = (N + 63) >> 6;           // 782

    unsigned char* ws = (unsigned char*)d_ws;
    size_t off = 0;
    __half* bufH    = (__half*)(ws + off); off += (size_t)N * 128 * sizeof(__half);
    __half* bufAcc  = (__half*)(ws + off); off += (size_t)N * 128 * sizeof(__half);
    int*    csr_src = (int*)(ws + off);    off += (size_t)E_tot * sizeof(int);
    int*    pairs   = (int*)(ws + off);    off += (size_t)E_tot * sizeof(int);
    float*  als     = (float*)(ws + off);  off += (size_t)N * 4 * sizeof(float);
    float*  ald     = (float*)(ws + off);  off += (size_t)N * 4 * sizeof(float);
    int*    offsets = (int*)(ws + off);    off += (size_t)(N + 1) * sizeof(int);
    int*    colTot  = (int*)(ws + off);    off += (size_t)NB * sizeof(int);
    int*    coarseOff = (int*)(ws + off);  off += (size_t)(NB + 1) * sizeof(int);
    int*    mint    = (int*)(ws + off);    off += 24 * sizeof(int);
    int*    cntmat  = (int*)(ws + off);    off += (size_t)NB * NBLK * sizeof(int);

    const int B = 256;
    const int gRows128 = (N + 127) / 128;
    const int gAgg  = 2048;

    // ===== CSR build (atomic-free; mint init fused into p1) =====
    p1_hist<<<NBLK, B, 0, stream>>>(src, dst, E_real, E_tot, NB, NBLK, EPB, cntmat, mint);
    p_scancols<<<NB, B, 0, stream>>>(cntmat, colTot, NBLK);
    p_scancoarse<<<1, B, 0, stream>>>(colTot, coarseOff, offsets, NB, N, E_tot);
    p2_scatter<<<NBLK, B, 0, stream>>>(src, dst, E_real, E_tot, NB, NBLK, EPB, cntmat, coarseOff, pairs);
    p3_bucket<<<NB, B, 0, stream>>>(pairs, coarseOff, NB, N, offsets, csr_src);

    // ===== Layer 0 =====
    gemm_mfma<8, 4, false><<<gRows128, B, 0, stream>>>(x, W0, a_src0, a_dst0, bufH, 128, als, ald, mint, N);
    gat_agg128<<<gAgg, B, 0, stream>>>(offsets, csr_src, bufH, als, ald, mint, b0, bufAcc, N);

    // ===== Layer 1 =====
    gemm_mfma<8, 4, true><<<gRows128, B, 0, stream>>>(bufAcc, W1, a_src1, a_dst1, bufH, 128, als, ald, mint + 8, N);
    gat_agg128<<<gAgg, B, 0, stream>>>(offsets, csr_src, bufH, als, ald, mint + 8, b1, bufAcc, N);

    // ===== Layer 2 =====
    gemm_mfma<3, 1, true><<<gRows128, B, 0, stream>>>(bufAcc, W2, a_src2, a_dst2, bufH, 40, als, ald, mint + 16, N);
    gat_agg40_lsm<<<gAgg, B, 0, stream>>>(offsets, csr_src, bufH, als, ald, mint + 16, b2,
                                          (float*)d_out, N);
}

// Round 14
// 198.915 us; speedup vs baseline: 1.0549x; 1.0549x over previous
//
#include <hip/hip_runtime.h>
#include <hip/hip_fp16.h>
#include <math.h>

typedef _Float16 f16x8 __attribute__((ext_vector_type(8)));
typedef _Float16 f16x4 __attribute__((ext_vector_type(4)));
typedef float f32x4 __attribute__((ext_vector_type(4)));

__device__ __forceinline__ int f2oi(float f) {
    int i = __float_as_int(f);
    return i >= 0 ? i : (i ^ 0x7FFFFFFF);
}
__device__ __forceinline__ float oi2f(int i) {
    return __int_as_float(i >= 0 ? i : (i ^ 0x7FFFFFFF));
}

// ---------- MFMA GEMM + fused logits + fused global-max ----------
template<int MT, int H, bool XF16>
__global__ __launch_bounds__(256) void gemm_mfma(const void* __restrict__ Xv,
                                                 const float* __restrict__ W,
                                                 const float* __restrict__ a_src,
                                                 const float* __restrict__ a_dst,
                                                 __half* __restrict__ Hout, int Mout,
                                                 float* __restrict__ als,
                                                 float* __restrict__ ald,
                                                 int* __restrict__ mint, int N) {
    constexpr int LDSB = (MT * 4096 > 16384) ? MT * 4096 : 16384;
    constexpr int HST = (MT == 8) ? 256 : 128;
    __shared__ char ldsb[LDSB];
    __shared__ int lmax[8];

    int tid = threadIdx.x;
    if (tid < 8) lmax[tid] = (int)0x80000000;

    const int nf4 = 16 * MT * 32;
    for (int idx = tid; idx < nf4; idx += 256) {
        int r = idx >> 5, c = idx & 31;
        float4 w = (r < Mout) ? reinterpret_cast<const float4*>(W)[(size_t)r * 32 + c]
                              : make_float4(0.f, 0.f, 0.f, 0.f);
        f16x4 hv;
        hv[0] = (_Float16)w.x; hv[1] = (_Float16)w.y;
        hv[2] = (_Float16)w.z; hv[3] = (_Float16)w.w;
        int byte = r * 256 + ((c * 8) ^ ((r & 7) << 4));
        *reinterpret_cast<f16x4*>(&ldsb[byte]) = hv;
    }
    __syncthreads();

    int l = tid & 63, wv = tid >> 6;
    int lr = l & 15, lk = l >> 4;
    f32x4 acc[2][MT];
#pragma unroll
    for (int rt = 0; rt < 2; rt++)
#pragma unroll
        for (int c = 0; c < MT; c++) acc[rt][c] = (f32x4){0.f, 0.f, 0.f, 0.f};

    const float* xpf[2];
    const __half* xph[2];
#pragma unroll
    for (int rt = 0; rt < 2; rt++) {
        int rg = blockIdx.x * 128 + rt * 64 + wv * 16 + lr;
        if (rg >= N) rg = N - 1;
        if (XF16) xph[rt] = (const __half*)Xv + (size_t)rg * 128 + lk * 8;
        else      xpf[rt] = (const float*)Xv + (size_t)rg * 128 + lk * 8;
    }

#pragma unroll
    for (int k0 = 0; k0 < 128; k0 += 32) {
        f16x8 a[2];
#pragma unroll
        for (int rt = 0; rt < 2; rt++) {
            if (XF16) {
                a[rt] = *reinterpret_cast<const f16x8*>(xph[rt] + k0);
            } else {
                float4 x0 = *reinterpret_cast<const float4*>(xpf[rt] + k0);
                float4 x1 = *reinterpret_cast<const float4*>(xpf[rt] + k0 + 4);
                a[rt][0] = (_Float16)x0.x; a[rt][1] = (_Float16)x0.y;
                a[rt][2] = (_Float16)x0.z; a[rt][3] = (_Float16)x0.w;
                a[rt][4] = (_Float16)x1.x; a[rt][5] = (_Float16)x1.y;
                a[rt][6] = (_Float16)x1.z; a[rt][7] = (_Float16)x1.w;
            }
        }
#pragma unroll
        for (int c = 0; c < MT; c++) {
            int n = 16 * c + lr;
            int byte = n * 256 + (((k0 + lk * 8) * 2) ^ ((n & 7) << 4));
            f16x8 b = *reinterpret_cast<const f16x8*>(&ldsb[byte]);
            acc[0][c] = __builtin_amdgcn_mfma_f32_16x16x32_f16(a[0], b, acc[0][c], 0, 0, 0);
            acc[1][c] = __builtin_amdgcn_mfma_f32_16x16x32_f16(a[1], b, acc[1][c], 0, 0, 0);
        }
    }
    __syncthreads();

#pragma unroll
    for (int rt = 0; rt < 2; rt++)
#pragma unroll
        for (int c = 0; c < MT; c++)
#pragma unroll
            for (int r = 0; r < 4; r++) {
                int rowl = rt * 64 + wv * 16 + lk * 4 + r;
                int col = 16 * c + lr;
                int byte = rowl * HST + ((col * 2) ^ ((rowl & 7) << 4));
                *reinterpret_cast<__half*>(&ldsb[byte]) = __float2half(acc[rt][c][r]);
            }
    __syncthreads();

    int row = tid >> 1, seg = tid & 1;
    int rowg = blockIdx.x * 128 + row;
    if (rowg < N) {
        const int rowB = Mout * 2;
        int segstart = (MT == 8) ? seg * 128 : seg * 48;
        int nch = (MT == 8) ? 8 : (seg ? 2 : 3);
        float hs[H], hd[H];
#pragma unroll
        for (int h = 0; h < H; h++) { hs[h] = 0.f; hd[h] = 0.f; }
        for (int i = 0; i < nch; i++) {
            int cb = segstart + i * 16;
            f16x8 v = *reinterpret_cast<const f16x8*>(
                &ldsb[row * HST + (cb ^ ((row & 7) << 4))]);
            *reinterpret_cast<f16x8*>((char*)Hout + (size_t)rowg * rowB + cb) = v;
            int hh = (H == 1) ? 0 : (cb >> 6);
            int colb = cb >> 1;
            float ps = 0.f, pd = 0.f;
#pragma unroll
            for (int j = 0; j < 8; j++) {
                float f = (float)v[j];
                ps = fmaf(f, a_src[colb + j], ps);
                pd = fmaf(f, a_dst[colb + j], pd);
            }
            hs[hh] += ps; hd[hh] += pd;
        }
        if (H == 4) {
#pragma unroll
            for (int t = 0; t < 2; t++) {
                int hh = 2 * seg + t;
                als[rowg * 4 + hh] = hs[hh];
                ald[rowg * 4 + hh] = hd[hh];
                atomicMax(&lmax[hh], f2oi(hs[hh]));
                atomicMax(&lmax[4 + hh], f2oi(hd[hh]));
            }
        } else {
            float s = hs[0] + __shfl_xor(hs[0], 1, 64);
            float d = hd[0] + __shfl_xor(hd[0], 1, 64);
            if (seg == 0) {
                als[rowg] = s; ald[rowg] = d;
                atomicMax(&lmax[0], f2oi(s));
                atomicMax(&lmax[4], f2oi(d));
            }
        }
    }
    __syncthreads();
    if (tid < H) atomicMax(&mint[tid], lmax[tid]);
    if (tid >= 8 && tid < 8 + H) atomicMax(&mint[4 + tid - 8], lmax[4 + tid - 8]);
}

// ---------- atomic-free CSR build (packed src<<16|dst pairs; N < 65536) ----------
__global__ __launch_bounds__(256) void p1_hist(const int* __restrict__ src,
                                               const int* __restrict__ dst,
                                               int E_real, int E_tot, int NB, int NBLK,
                                               int EPB, int* __restrict__ cntmat,
                                               int* __restrict__ mint) {
    if (blockIdx.x == 0 && threadIdx.x < 24) mint[threadIdx.x] = (int)0x80000000;
    __shared__ int hist[1024];
    for (int i = threadIdx.x; i < NB; i += 256) hist[i] = 0;
    __syncthreads();
    int e0 = blockIdx.x * EPB;
    int e1 = min(e0 + EPB, E_tot);
    for (int e = e0 + threadIdx.x; e < e1; e += 256) {
        int d = (e < E_real) ? dst[e] : e - E_real;
        atomicAdd(&hist[d >> 6], 1);
    }
    __syncthreads();
    for (int b = threadIdx.x; b < NB; b += 256)
        cntmat[b * NBLK + blockIdx.x] = hist[b];
}

// parallel Hillis-Steele scan of each bucket's block-counts
__global__ __launch_bounds__(256) void p_scancols(int* __restrict__ cntmat,
                                                  int* __restrict__ colTot, int NBLK) {
    __shared__ int sh[256];
    int b = blockIdx.x;
    int t = threadIdx.x;
    int v = (t < NBLK) ? cntmat[b * NBLK + t] : 0;
    sh[t] = v;
    __syncthreads();
    for (int off = 1; off < 256; off <<= 1) {
        int u = (t >= off) ? sh[t - off] : 0;
        __syncthreads();
        sh[t] += u;
        __syncthreads();
    }
    if (t < NBLK) cntmat[b * NBLK + t] = sh[t] - v;   // exclusive
    if (t == 255) colTot[b] = sh[255];
}

__global__ __launch_bounds__(256) void p_scancoarse(const int* __restrict__ colTot,
                                                    int* __restrict__ coarseOff,
                                                    int* __restrict__ offsets,
                                                    int NB, int N, int E_tot) {
    __shared__ int sh[256];
    int t = threadIdx.x, base = t * 4;
    int v0 = 0, v1 = 0, v2 = 0, v3 = 0;
    if (base + 0 < NB) v0 = colTot[base + 0];
    if (base + 1 < NB) v1 = colTot[base + 1];
    if (base + 2 < NB) v2 = colTot[base + 2];
    if (base + 3 < NB) v3 = colTot[base + 3];
    int s = v0 + v1 + v2 + v3;
    sh[t] = s;
    __syncthreads();
    for (int off = 1; off < 256; off <<= 1) {
        int u = (t >= off) ? sh[t - off] : 0;
        __syncthreads();
        sh[t] += u;
        __syncthreads();
    }
    int run = sh[t] - s;
    if (base + 0 < NB) { coarseOff[base + 0] = run; run += v0; }
    if (base + 1 < NB) { coarseOff[base + 1] = run; run += v1; }
    if (base + 2 < NB) { coarseOff[base + 2] = run; run += v2; }
    if (base + 3 < NB) { coarseOff[base + 3] = run; }
    if (t == 255) { coarseOff[NB] = sh[255]; offsets[N] = E_tot; }
}

__global__ __launch_bounds__(256) void p2_scatter(const int* __restrict__ src,
                                                  const int* __restrict__ dst,
                                                  int E_real, int E_tot, int NB, int NBLK,
                                                  int EPB, const int* __restrict__ cntmat,
                                                  const int* __restrict__ coarseOff,
                                                  int* __restrict__ pairs) {
    __shared__ int cur[1024];
    for (int b = threadIdx.x; b < NB; b += 256)
        cur[b] = coarseOff[b] + cntmat[b * NBLK + blockIdx.x];
    __syncthreads();
    int e0 = blockIdx.x * EPB;
    int e1 = min(e0 + EPB, E_tot);
    for (int e = e0 + threadIdx.x; e < e1; e += 256) {
        int s, d;
        if (e < E_real) { s = src[e]; d = dst[e]; } else { s = d = e - E_real; }
        int pos = atomicAdd(&cur[d >> 6], 1);
        pairs[pos] = (s << 16) | d;
    }
}

__global__ __launch_bounds__(256) void p3_bucket(const int* __restrict__ pairs,
                                                 const int* __restrict__ coarseOff,
                                                 int NB, int N, int* __restrict__ offsets,
                                                 int* __restrict__ csr_src) {
    __shared__ int lh[64], lc[64];
    int b = blockIdx.x;
    int beg = coarseOff[b], end = coarseOff[b + 1];
    int t = threadIdx.x;
    if (t < 64) lh[t] = 0;
    __syncthreads();
    for (int i = beg + t; i < end; i += 256)
        atomicAdd(&lh[pairs[i] & 63], 1);
    __syncthreads();
    if (t < 64) {
        int v = lh[t];
        int run = v;
#pragma unroll
        for (int off = 1; off < 64; off <<= 1) {
            int o = __shfl_up(run, off, 64);
            if (t >= off) run += o;
        }
        int ex = run - v;
        lc[t] = ex;
        int node = b * 64 + t;
        if (node < N) offsets[node] = beg + ex;
    }
    __syncthreads();
    for (int i = beg + t; i < end; i += 256) {
        int pk = pairs[i];
        int pos = atomicAdd(&lc[pk & 63], 1);
        csr_src[beg + pos] = ((unsigned)pk) >> 16;
    }
}

// ---------- GAT aggregate, layers 0/1 (H=4,C=32): 4 edges in flight, fp16 out ----------
__global__ __launch_bounds__(256) void gat_agg128(const int* __restrict__ offsets,
                                                  const int* __restrict__ csr_src,
                                                  const __half* __restrict__ h,
                                                  const float* __restrict__ als,
                                                  const float* __restrict__ ald,
                                                  const int* __restrict__ mint,
                                                  const float* __restrict__ bias,
                                                  __half* __restrict__ out, int N) {
    __shared__ float wlds[4][64][4];
    __shared__ int   slds[4][64];
    int wid = threadIdx.x >> 6;
    int lane = threadIdx.x & 63;
    int g = lane >> 4, j = lane & 15, hd = j >> 2;
    int gwid = (blockIdx.x * 256 + threadIdx.x) >> 6;
    int nWaves = (gridDim.x * 256) >> 6;
    const char* hb = (const char*)h;
    const float4* als4 = (const float4*)als;
    const float4* ald4 = (const float4*)ald;

    float4 shiftv;
    {
        float v;
        v = oi2f(mint[0]) + oi2f(mint[4]); shiftv.x = v > 0.f ? v : 0.2f * v;
        v = oi2f(mint[1]) + oi2f(mint[5]); shiftv.y = v > 0.f ? v : 0.2f * v;
        v = oi2f(mint[2]) + oi2f(mint[6]); shiftv.z = v > 0.f ? v : 0.2f * v;
        v = oi2f(mint[3]) + oi2f(mint[7]); shiftv.w = v > 0.f ? v : 0.2f * v;
    }
    float4 bv0 = ((const float4*)bias)[j * 2];
    float4 bv1 = ((const float4*)bias)[j * 2 + 1];

    for (int n = gwid; n < N; n += nWaves) {
        int beg = offsets[n], end = offsets[n + 1];
        float4 adn = ald4[n];
        float acc[8];
#pragma unroll
        for (int k = 0; k < 8; k++) acc[k] = 0.f;
        float den = 0.f;

        for (int c0 = beg; c0 < end; c0 += 64) {
            int e = c0 + lane;
            int s = 0;
            float4 w = make_float4(0.f, 0.f, 0.f, 0.f);
            if (e < end) {
                s = csr_src[e];
                float4 a4 = als4[s];
                float v;
                v = a4.x + adn.x; v = v > 0.f ? v : 0.2f * v; w.x = __expf(v - shiftv.x);
                v = a4.y + adn.y; v = v > 0.f ? v : 0.2f * v; w.y = __expf(v - shiftv.y);
                v = a4.z + adn.z; v = v > 0.f ? v : 0.2f * v; w.z = __expf(v - shiftv.z);
                v = a4.w + adn.w; v = v > 0.f ? v : 0.2f * v; w.w = __expf(v - shiftv.w);
            }
            *reinterpret_cast<float4*>(&wlds[wid][lane][0]) = w;
            slds[wid][lane] = s;
            int cnt = end - c0; if (cnt > 64) cnt = 64;
            int quads = (cnt + 3) >> 2;
            for (int q = 0; q < quads; ++q) {
                int ec = q * 4 + g;
                int s0 = slds[wid][ec];
                float w0 = wlds[wid][ec][hd];
                f16x8 hv = *reinterpret_cast<const f16x8*>(
                    hb + (unsigned)(s0 * 256 + j * 16));
                den += w0;
#pragma unroll
                for (int k = 0; k < 8; k++)
                    acc[k] = fmaf((float)hv[k], w0, acc[k]);
            }
        }
#pragma unroll
        for (int off = 16; off <= 32; off <<= 1) {
            den += __shfl_xor(den, off, 64);
#pragma unroll
            for (int k = 0; k < 8; k++) acc[k] += __shfl_xor(acc[k], off, 64);
        }
        if (g == 0) {
            float inv = 1.f / den;
            f16x8 ov;
            float bvv[8] = {bv0.x, bv0.y, bv0.z, bv0.w, bv1.x, bv1.y, bv1.z, bv1.w};
#pragma unroll
            for (int k = 0; k < 8; k++) {
                float r = acc[k] * inv + bvv[k];
                r = r > 0.f ? r : __expf(r) - 1.f;
                ov[k] = (_Float16)r;
            }
            *reinterpret_cast<f16x8*>((char*)out + (size_t)n * 256 + j * 16) = ov;
        }
    }
}

// ---------- GAT aggregate + log_softmax, layer 2 (H=1,C=40) ----------
__global__ __launch_bounds__(256) void gat_agg40_lsm(const int* __restrict__ offsets,
                                                     const int* __restrict__ csr_src,
                                                     const __half* __restrict__ h,
                                                     const float* __restrict__ als,
                                                     const float* __restrict__ ald,
                                                     const int* __restrict__ mint,
                                                     const float* __restrict__ b2,
                                                     float* __restrict__ out, int N) {
    __shared__ float wlds[4][64];
    __shared__ int   slds[4][64];
    int wid = threadIdx.x >> 6;
    int lane = threadIdx.x & 63;
    int g = lane >> 4, j = lane & 15;
    int gwid = (blockIdx.x * 256 + threadIdx.x) >> 6;
    int nWaves = (gridDim.x * 256) >> 6;
    const char* hb = (const char*)h;

    float shift;
    {
        float v = oi2f(mint[0]) + oi2f(mint[4]);
        shift = v > 0.f ? v : 0.2f * v;
    }
    float4 bv = (j < 10) ? ((const float4*)b2)[j] : make_float4(0.f, 0.f, 0.f, 0.f);

    for (int n = gwid; n < N; n += nWaves) {
        int beg = offsets[n], end = offsets[n + 1];
        float adn = ald[n];
        float acc[4];
#pragma unroll
        for (int k = 0; k < 4; k++) acc[k] = 0.f;
        float den = 0.f;

        for (int c0 = beg; c0 < end; c0 += 64) {
            int e = c0 + lane;
            int s = 0;
            float wv = 0.f;
            if (e < end) {
                s = csr_src[e];
                float v = als[s] + adn; v = v > 0.f ? v : 0.2f * v;
                wv = __expf(v - shift);
            }
            wlds[wid][lane] = wv;
            slds[wid][lane] = s;
            int cnt = end - c0; if (cnt > 64) cnt = 64;
            int quads = (cnt + 3) >> 2;
            for (int q = 0; q < quads; ++q) {
                int ec = q * 4 + g;
                int s0 = slds[wid][ec];
                float w0 = wlds[wid][ec];
                den += w0;
                if (j < 10) {
                    f16x4 hv = *reinterpret_cast<const f16x4*>(
                        hb + (unsigned)(s0 * 80 + j * 8));
#pragma unroll
                    for (int k = 0; k < 4; k++)
                        acc[k] = fmaf((float)hv[k], w0, acc[k]);
                }
            }
        }
#pragma unroll
        for (int off = 16; off <= 32; off <<= 1) {
            den += __shfl_xor(den, off, 64);
#pragma unroll
            for (int k = 0; k < 4; k++) acc[k] += __shfl_xor(acc[k], off, 64);
        }
        float inv = 1.f / den;
        float val[4];
        float m = -INFINITY;
#pragma unroll
        for (int k = 0; k < 4; k++) {
            val[k] = (j < 10) ? acc[k] * inv + ((const float*)&bv)[k] : -INFINITY;
            m = fmaxf(m, val[k]);
        }
#pragma unroll
        for (int off = 8; off >= 1; off >>= 1) m = fmaxf(m, __shfl_xor(m, off, 64));
        float pe = 0.f;
#pragma unroll
        for (int k = 0; k < 4; k++)
            if (j < 10) pe += __expf(val[k] - m);
#pragma unroll
        for (int off = 8; off >= 1; off >>= 1) pe += __shfl_xor(pe, off, 64);
        if (g == 0 && j < 10) {
            float lsum = __logf(pe);
            float4 o;
            o.x = val[0] - m - lsum;
            o.y = val[1] - m - lsum;
            o.z = val[2] - m - lsum;
            o.w = val[3] - m - lsum;
            ((float4*)(out + (size_t)n * 40))[j] = o;
        }
    }
}

extern "C" void kernel_launch(void* const* d_in, const int* in_sizes, int n_in,
                              void* d_out, int out_size, void* d_ws, size_t ws_size,
                              hipStream_t stream) {
    const float* x      = (const float*)d_in[0];
    const int*   ei     = (const int*)d_in[1];
    const float* W0     = (const float*)d_in[2];
    const float* a_src0 = (const float*)d_in[3];
    const float* a_dst0 = (const float*)d_in[4];
    const float* b0     = (const float*)d_in[5];
    const float* W1     = (const float*)d_in[6];
    const float* a_src1 = (const float*)d_in[7];
    const float* a_dst1 = (const float*)d_in[8];
    const float* b1     = (const float*)d_in[9];
    const float* W2     = (const float*)d_in[10];
    const float* a_src2 = (const float*)d_in[11];
    const float* a_dst2 = (const float*)d_in[12];
    const float* b2     = (const float*)d_in[13];

    const int N = in_sizes[0] / 128;          // 50000  (< 65536, required for packing)
    const int E_real = in_sizes[1] / 2;       // 800000
    const int E_tot = E_real + N;
    const int* src = ei;
    const int* dst = ei + E_real;

    const int EPB  = 4096;
    const int NBLK = (E_tot + EPB - 1) / EPB; // 208
    const int NB   = (N + 63) >> 6;           // 782

    unsigned char* ws = (unsigned char*)d_ws;
    size_t off = 0;
    __half* bufH    = (__half*)(ws + off); off += (size_t)N * 128 * sizeof(__half);
    __half* bufAcc  = (__half*)(ws + off); off += (size_t)N * 128 * sizeof(__half);
    int*    csr_src = (int*)(ws + off);    off += (size_t)E_tot * sizeof(int);
    int*    pairs   = (int*)(ws + off);    off += (size_t)E_tot * sizeof(int);
    float*  als     = (float*)(ws + off);  off += (size_t)N * 4 * sizeof(float);
    float*  ald     = (float*)(ws + off);  off += (size_t)N * 4 * sizeof(float);
    int*    offsets = (int*)(ws + off);    off += (size_t)(N + 1) * sizeof(int);
    int*    colTot  = (int*)(ws + off);    off += (size_t)NB * sizeof(int);
    int*    coarseOff = (int*)(ws + off);  off += (size_t)(NB + 1) * sizeof(int);
    int*    mint    = (int*)(ws + off);    off += 24 * sizeof(int);
    int*    cntmat  = (int*)(ws + off);    off += (size_t)NB * NBLK * sizeof(int);

    const int B = 256;
    const int gRows128 = (N + 127) / 128;
    const int gAgg  = 2048;

    // ===== CSR build (atomic-free; mint init fused into p1) =====
    p1_hist<<<NBLK, B, 0, stream>>>(src, dst, E_real, E_tot, NB, NBLK, EPB, cntmat, mint);
    p_scancols<<<NB, B, 0, stream>>>(cntmat, colTot, NBLK);
    p_scancoarse<<<1, B, 0, stream>>>(colTot, coarseOff, offsets, NB, N, E_tot);
    p2_scatter<<<NBLK, B, 0, stream>>>(src, dst, E_real, E_tot, NB, NBLK, EPB, cntmat, coarseOff, pairs);
    p3_bucket<<<NB, B, 0, stream>>>(pairs, coarseOff, NB, N, offsets, csr_src);

    // ===== Layer 0 =====
    gemm_mfma<8, 4, false><<<gRows128, B, 0, stream>>>(x, W0, a_src0, a_dst0, bufH, 128, als, ald, mint, N);
    gat_agg128<<<gAgg, B, 0, stream>>>(offsets, csr_src, bufH, als, ald, mint, b0, bufAcc, N);

    // ===== Layer 1 =====
    gemm_mfma<8, 4, true><<<gRows128, B, 0, stream>>>(bufAcc, W1, a_src1, a_dst1, bufH, 128, als, ald, mint + 8, N);
    gat_agg128<<<gAgg, B, 0, stream>>>(offsets, csr_src, bufH, als, ald, mint + 8, b1, bufAcc, N);

    // ===== Layer 2 =====
    gemm_mfma<3, 1, true><<<gRows128, B, 0, stream>>>(bufAcc, W2, a_src2, a_dst2, bufH, 40, als, ald, mint + 16, N);
    gat_agg40_lsm<<<gAgg, B, 0, stream>>>(offsets, csr_src, bufH, als, ald, mint + 16, b2,
                                          (float*)d_out, N);
}